// Round 1
// baseline (738.502 us; speedup 1.0000x reference)
//
#include <hip/hip_runtime.h>
#include <math.h>

#define BATCH 4096
#define HID   1024
#define KDIM  1024
#define NSTEP 15
#define KV    3072      // virtual K: [A_hi·B_hi | A_hi·B_lo | A_lo·B_hi]
#define NCHUNK (KV / 64)

// MFMA GEMM: 256 threads = 4 waves; tile 128(M) x 64(N); BK=64 virtual-k.
// Wave w: rows (w&1)*64, cols (w>>1)*32; frags 4(M) x 2(N) of 16x16x32 f16.
// Depth-2 register prefetch + double-buffered LDS + raw s_barrier (no vmcnt
// drain): loads for chunk c+2 stay in flight across the barrier (T3/T4).
#define TMM 128
#define TNN 64
#define LDAH 72         // LDS row stride in halfs (144B)

typedef _Float16 half8 __attribute__((ext_vector_type(8)));
typedef float floatx4 __attribute__((ext_vector_type(4)));

__device__ __forceinline__ _Float16 f16hi(float x) { return (_Float16)x; }

// Barrier that does NOT drain vmcnt: explicit lgkmcnt(0) for LDS visibility,
// memory clobbers on both sides so ds ops can't migrate across (m201 idiom).
__device__ __forceinline__ void barrier_ls() {
    asm volatile("s_waitcnt lgkmcnt(0)" ::: "memory");
    __builtin_amdgcn_s_barrier();
    asm volatile("" ::: "memory");
}

// B3[n][kv]: kv<1024: hi(W[n][kv]); 1024..2047: lo; 2048..3071: hi (dup).
// Also: split inputs/hidden into f16 hi/lo, init lists/accums.
__global__ __launch_bounds__(256) void setup_kernel(
    const float* __restrict__ W_ih, const float* __restrict__ W_hh,
    const float* __restrict__ inputs, const float* __restrict__ hidden,
    _Float16* __restrict__ B3ih, _Float16* __restrict__ B3hh,
    _Float16* __restrict__ Ihi, _Float16* __restrict__ Ilo,
    _Float16* __restrict__ Hhi, _Float16* __restrict__ Hlo,
    float* __restrict__ flagcol, int* __restrict__ list0, int* __restrict__ counts,
    float* __restrict__ halt_accum, float* __restrict__ tot_rem) {
    size_t idx = (size_t)blockIdx.x * 256 + threadIdx.x;   // grid 16384 -> 4M
    {   // split inputs -> I, hidden -> H
        float x = inputs[idx];
        _Float16 h = f16hi(x);
        Ihi[idx] = h; Ilo[idx] = (_Float16)(x - (float)h);
        float y = hidden[idx];
        _Float16 g = f16hi(y);
        Hhi[idx] = g; Hlo[idx] = (_Float16)(y - (float)g);
    }
    if (idx < (size_t)KDIM * KDIM) {
        int n = (int)(idx >> 10), k = (int)(idx & 1023);
        float w = W_hh[idx];
        _Float16 hi = f16hi(w);
        _Float16 lo = (_Float16)(w - (float)hi);
        size_t base = (size_t)n * KV;
        B3hh[base + k] = hi; B3hh[base + 1024 + k] = lo; B3hh[base + 2048 + k] = hi;
        float w2 = W_ih[(size_t)n * 1025 + k];
        _Float16 hi2 = f16hi(w2);
        _Float16 lo2 = (_Float16)(w2 - (float)hi2);
        B3ih[base + k] = hi2; B3ih[base + 1024 + k] = lo2; B3ih[base + 2048 + k] = hi2;
    }
    if (idx < BATCH) { list0[idx] = idx; halt_accum[idx] = 0.f; tot_rem[idx] = 0.f; }
    if (idx < KDIM) flagcol[idx] = W_ih[idx * 1025 + 1024];
    if (idx < 16) counts[idx] = (idx == 0) ? BATCH : 0;
}

// mode 0: xout[row] = A @ B^T + bias (fp32)
// mode 1: h = tanh(acc + xbase + flag*flagcol + bias); store h fp32 + hi/lo f16
__global__ __launch_bounds__(256) void mfma_step_kernel(
    const _Float16* __restrict__ Ahi, const _Float16* __restrict__ Alo,
    const _Float16* __restrict__ B3, const float* __restrict__ bias,
    const float* __restrict__ xbase, const float* __restrict__ flagcol, float flag,
    const int* __restrict__ list, const int* __restrict__ pcount,
    float* __restrict__ hout, _Float16* __restrict__ houthi, _Float16* __restrict__ houtlo,
    float* __restrict__ xout, int mode) {
    int count = pcount ? *pcount : BATCH;
    int row0 = blockIdx.x * TMM;
    if (row0 >= count) return;
    int col0 = blockIdx.y * TNN;

    __shared__ _Float16 Asm[2][TMM][LDAH];
    __shared__ _Float16 Bsm[2][TNN][LDAH];

    int t = threadIdx.x;
    int lane = t & 63, w = t >> 6;
    int wm = (w & 1) * 64, wn = (w >> 1) * 32;

    // A staging: 128 rows x 8 half8-quads = 1024 quads, 4/thread (gathered rows)
    int arw[4], aq8[4]; size_t aoff[4];
#pragma unroll
    for (int l = 0; l < 4; l++) {
        int q = t + l * 256;
        int r = q >> 3, qk = q & 7;
        arw[l] = r; aq8[l] = qk * 8;
        int rr = row0 + r;
        int g = (rr < count) ? (list ? list[rr] : rr) : 0;
        aoff[l] = (size_t)g * KDIM + qk * 8;
    }
    // B staging: 64 n-rows x 8 quads = 512 quads, 2/thread
    int brw[2], bq8[2]; size_t boff[2];
#pragma unroll
    for (int l = 0; l < 2; l++) {
        int q = t + l * 256;
        int r = q >> 3, qk = q & 7;
        brw[l] = r; bq8[l] = qk * 8;
        boff[l] = (size_t)(col0 + r) * KV + qk * 8;
    }

    floatx4 acc[4][2];
#pragma unroll
    for (int i = 0; i < 4; i++)
#pragma unroll
        for (int j = 0; j < 2; j++) acc[i][j] = (floatx4)(0.f);

    int l15 = lane & 15, l4 = lane >> 4;

    // -------- depth-2 pipelined K-loop --------
    half8 avE[4], bvE[2];   // even-chunk register set
    half8 avO[4], bvO[2];   // odd-chunk register set

#define ISSUE(avS, bvS, c) do {                                               \
        int k0v_ = (c) << 6;                                                  \
        const _Float16* Asrc_ = (k0v_ < 2048) ? Ahi : Alo; /* segs [hi,hi,lo] */ \
        int kp_ = k0v_ & 1023;                                                \
        _Pragma("unroll")                                                     \
        for (int l = 0; l < 4; l++) avS[l] = *(const half8*)(Asrc_ + aoff[l] + kp_); \
        _Pragma("unroll")                                                     \
        for (int l = 0; l < 2; l++) bvS[l] = *(const half8*)(B3 + boff[l] + k0v_);   \
    } while (0)

#define LDSW(buf, avS, bvS) do {                                              \
        _Pragma("unroll")                                                     \
        for (int l = 0; l < 4; l++) *(half8*)(&Asm[buf][arw[l]][aq8[l]]) = avS[l]; \
        _Pragma("unroll")                                                     \
        for (int l = 0; l < 2; l++) *(half8*)(&Bsm[buf][brw[l]][bq8[l]]) = bvS[l]; \
    } while (0)

#define MFMA_CHUNK(buf) do {                                                  \
        _Pragma("unroll")                                                     \
        for (int ks = 0; ks < 2; ks++) {                                      \
            int ko = ks * 32 + l4 * 8;                                        \
            half8 af[4], bf[2];                                               \
            _Pragma("unroll")                                                 \
            for (int fi = 0; fi < 4; fi++)                                    \
                af[fi] = *(const half8*)(&Asm[buf][wm + fi * 16 + l15][ko]);  \
            _Pragma("unroll")                                                 \
            for (int fj = 0; fj < 2; fj++)                                    \
                bf[fj] = *(const half8*)(&Bsm[buf][wn + fj * 16 + l15][ko]);  \
            _Pragma("unroll")                                                 \
            for (int fi = 0; fi < 4; fi++)                                    \
                _Pragma("unroll")                                             \
                for (int fj = 0; fj < 2; fj++)                                \
                    acc[fi][fj] = __builtin_amdgcn_mfma_f32_16x16x32_f16(     \
                        af[fi], bf[fj], acc[fi][fj], 0, 0, 0);                \
        }                                                                     \
    } while (0)

    // prologue: buf0 <- c0; setO holds c1 (in flight)
    ISSUE(avE, bvE, 0);
    ISSUE(avO, bvO, 1);
    LDSW(0, avE, bvE);          // compiler waits vmcnt for setE only (counted)
    barrier_ls();

    for (int it = 0; it < NCHUNK; it += 2) {
        // even body: chunk it in buf0; setO holds it+1; setE free
        if (it + 2 < NCHUNK) ISSUE(avE, bvE, it + 2);
        MFMA_CHUNK(0);
        LDSW(1, avO, bvO);      // counted vmcnt: setE loads stay in flight
        barrier_ls();
        // odd body: chunk it+1 in buf1; setE holds it+2; setO free
        if (it + 3 < NCHUNK) ISSUE(avO, bvO, it + 3);
        MFMA_CHUNK(1);
        if (it + 2 < NCHUNK) LDSW(0, avE, bvE);
        barrier_ls();
    }

#undef ISSUE
#undef LDSW
#undef MFMA_CHUNK

    // epilogue: C/D layout col = lane&15, row = (lane>>4)*4 + reg  [m89-verified]
#pragma unroll
    for (int fi = 0; fi < 4; fi++) {
#pragma unroll
        for (int rr = 0; rr < 4; rr++) {
            int lm = wm + fi * 16 + l4 * 4 + rr;
            int grd = row0 + lm;
            if (grd >= count) continue;
            int g = list ? list[grd] : grd;
#pragma unroll
            for (int fj = 0; fj < 2; fj++) {
                int c = col0 + wn + fj * 16 + l15;
                float v = acc[fi][fj][rr];
                if (mode == 0) {
                    xout[(size_t)g * KDIM + c] = v + bias[c];
                } else {
                    v += xbase[(size_t)g * KDIM + c] + flag * flagcol[c] + bias[c];
                    v = tanhf(v);
                    hout[(size_t)g * KDIM + c] = v;
                    _Float16 hi = f16hi(v);
                    houthi[(size_t)g * KDIM + c] = hi;
                    houtlo[(size_t)g * KDIM + c] = (_Float16)(v - (float)hi);
                }
            }
        }
    }
}

// One wave per active row: halt logit, sigmoid, halting state machine,
// tot_h accumulation into d_out, compaction of next-step list.  (R1-verified)
__global__ __launch_bounds__(256) void halt_kernel(
    const float* __restrict__ h, const float* __restrict__ W_halt,
    const float* __restrict__ b_halt,
    const int* __restrict__ list, const int* __restrict__ pcount,
    int* __restrict__ list_next, int* __restrict__ pcount_next,
    float* __restrict__ halt_accum, float* __restrict__ tot_rem,
    float* __restrict__ tot_h, float* __restrict__ steps_out,
    int stepnum, int first) {
    int count = *pcount;
    int wid = threadIdx.x >> 6, lane = threadIdx.x & 63;
    int r = blockIdx.x * 4 + wid;
    if (r >= count) return;
    int row = list[r];
    const float* hr = h + (size_t)row * HID;

    float dot = 0.f;
#pragma unroll
    for (int q = 0; q < 4; q++) {
        int c = q * 256 + lane * 4;
        float4 hv = *(const float4*)(hr + c);
        float4 wv = *(const float4*)(W_halt + c);
        dot += hv.x * wv.x + hv.y * wv.y + hv.z * wv.z + hv.w * wv.w;
    }
#pragma unroll
    for (int off = 32; off > 0; off >>= 1) dot += __shfl_down(dot, off);

    float combined = 0.f;
    if (lane == 0) {
        float p = 1.f / (1.f + expf(-(dot + b_halt[0])));
        float S = halt_accum[row] + p;
        halt_accum[row] = S;
        tot_rem[row] += p;
        bool ending = (S + p) > 0.99f;      // budget = 1 - PONDER_EPS
        if (ending) {
            combined = p + (1.f - S);
            steps_out[row] = (float)stepnum;
        } else {
            combined = p;
            int idx = atomicAdd(pcount_next, 1);
            list_next[idx] = row;
        }
    }
    combined = __shfl(combined, 0);

    float* th = tot_h + (size_t)row * HID;
#pragma unroll
    for (int q = 0; q < 4; q++) {
        int c = q * 256 + lane * 4;
        float4 hv = *(const float4*)(hr + c);
        float4 ov;
        if (first) {
            ov.x = combined * hv.x; ov.y = combined * hv.y;
            ov.z = combined * hv.z; ov.w = combined * hv.w;
        } else {
            ov = *(const float4*)(th + c);
            ov.x += combined * hv.x; ov.y += combined * hv.y;
            ov.z += combined * hv.z; ov.w += combined * hv.w;
        }
        *(float4*)(th + c) = ov;
    }
}

// blocks 0..1023: survivors get (1 - halt_accum) * h_final, steps = 16.
// block 1024: ponder reduction.
__global__ __launch_bounds__(256) void epilogue_kernel(
    const float* __restrict__ h, const int* __restrict__ list,
    const int* __restrict__ pcount, const float* __restrict__ halt_accum,
    const float* __restrict__ tot_rem,
    float* __restrict__ tot_h, float* __restrict__ steps_out,
    float* __restrict__ ponder) {
    if (blockIdx.x == 1024) {
        __shared__ float red[4];
        int t = threadIdx.x;
        float v = 0.f;
#pragma unroll
        for (int i = 0; i < 16; i++) v += tot_rem[t + i * 256];
#pragma unroll
        for (int off = 32; off > 0; off >>= 1) v += __shfl_down(v, off);
        int lane = t & 63, wid = t >> 6;
        if (lane == 0) red[wid] = v;
        __syncthreads();
        if (t == 0) ponder[0] = (red[0] + red[1] + red[2] + red[3]) * (-0.01f / 4096.f);
        return;
    }
    int count = *pcount;
    int wid = threadIdx.x >> 6, lane = threadIdx.x & 63;
    int r = blockIdx.x * 4 + wid;
    if (r >= count) return;
    int row = list[r];
    float cmb = 1.f - halt_accum[row];
    if (lane == 0) steps_out[row] = 16.f;
    const float* hr = h + (size_t)row * HID;
    float* th = tot_h + (size_t)row * HID;
#pragma unroll
    for (int q = 0; q < 4; q++) {
        int c = q * 256 + lane * 4;
        float4 hv = *(const float4*)(hr + c);
        float4 ov = *(const float4*)(th + c);
        ov.x += cmb * hv.x; ov.y += cmb * hv.y;
        ov.z += cmb * hv.z; ov.w += cmb * hv.w;
        *(float4*)(th + c) = ov;
    }
}

extern "C" void kernel_launch(void* const* d_in, const int* in_sizes, int n_in,
                              void* d_out, int out_size, void* d_ws, size_t ws_size,
                              hipStream_t stream) {
    const float* inputs = (const float*)d_in[0];
    const float* hidden = (const float*)d_in[1];
    const float* W_ih   = (const float*)d_in[2];
    const float* b_ih   = (const float*)d_in[3];
    const float* W_hh   = (const float*)d_in[4];
    const float* b_hh   = (const float*)d_in[5];
    const float* W_halt = (const float*)d_in[6];
    const float* b_halt = (const float*)d_in[7];
    float* out = (float*)d_out;

    float* ws = (float*)d_ws;
    const size_t NM = (size_t)BATCH * HID;               // 4M
    float* xbase = ws;                                   // 4M f32
    float* h     = xbase + NM;                           // 4M f32
    _Float16* B3ih = (_Float16*)(h + NM);                // 1024*3072 halfs
    _Float16* B3hh = B3ih + (size_t)HID * KV;
    _Float16* Ahi0 = B3hh + (size_t)HID * KV;            // 4M halfs each
    _Float16* Alo0 = Ahi0 + NM;
    _Float16* Ahi1 = Alo0 + NM;
    _Float16* Alo1 = Ahi1 + NM;
    float* flagcol = (float*)(Alo1 + NM);                // 1024
    float* halt_accum = flagcol + KDIM;                  // 4096
    float* tot_rem = halt_accum + BATCH;                 // 4096
    int* list0 = (int*)(tot_rem + BATCH);                // 4096
    int* list1 = list0 + BATCH;                          // 4096
    int* counts = list1 + BATCH;                         // 16

    _Float16* Ahi[2] = {Ahi0, Ahi1};
    _Float16* Alo[2] = {Alo0, Alo1};
    int* lists[2] = {list0, list1};

    float* tot_h = out;
    float* ponder = out + NM;
    float* steps_out = ponder + 1;

    // setup + split fused: inputs -> buf1 (dead after x_base), hidden -> buf0
    setup_kernel<<<16384, 256, 0, stream>>>(W_ih, W_hh, inputs, hidden,
                                            B3ih, B3hh, Ahi1, Alo1, Ahi0, Alo0,
                                            flagcol, list0, counts, halt_accum, tot_rem);

    // x_base = inputs @ W_ih[:, :-1].T + b_ih
    mfma_step_kernel<<<dim3(32, 16), 256, 0, stream>>>(
        Ahi1, Alo1, B3ih, b_ih, nullptr, nullptr, 0.f, nullptr, nullptr,
        nullptr, nullptr, nullptr, xbase, 0);

    for (int t = 0; t < NSTEP; t++) {
        mfma_step_kernel<<<dim3(32, 16), 256, 0, stream>>>(
            Ahi[t & 1], Alo[t & 1], B3hh, b_hh, xbase, flagcol,
            (t == 0) ? 1.f : 0.f, lists[t & 1], counts + t,
            h, Ahi[(t + 1) & 1], Alo[(t + 1) & 1], nullptr, 1);
        halt_kernel<<<1024, 256, 0, stream>>>(h, W_halt, b_halt,
                                              lists[t & 1], counts + t,
                                              lists[(t + 1) & 1], counts + t + 1,
                                              halt_accum, tot_rem, tot_h, steps_out,
                                              t + 1, (t == 0) ? 1 : 0);
    }
    epilogue_kernel<<<1025, 256, 0, stream>>>(h, lists[1], counts + 15,
                                              halt_accum, tot_rem, tot_h, steps_out, ponder);
}